// Round 3
// baseline (911.722 us; speedup 1.0000x reference)
//
#include <hip/hip_runtime.h>
#include <stdint.h>

// MHGCN: out = 0.5*(h1+h2); h1 = sym@(x@w0)+b0; h2 = sym@(h1@w1)+b1
// sym = (adj·rw) + (adj·rw)^T. N=8192, IN_F=256, OUT_F=128, R=2.
// Round 6: SPLITK 8->4 (halves P partial-buffer traffic), xw0 merged
// into the sym launch as role-split blocks (one fewer launch; xw0 ALU
// hides under sym's BW phase).
//
// ws layout (fast path):
//   [0,2MB)      xw0T  bf16 [128][8192]
//   [2,4MB)      hwT   bf16 [128][8192]
//   [4,8MB)      h1    f32  [8192][128]
//   [8,12MB)     h2    f32  (fallback path only)
//   [13,141MB)   sym   bf16 [8192][8192]
//   [144,161MB)  P     f32  [SPLITK][8192][128] partials

#define NN 8192
#define KIN 256
#define FOUT 128
#define SPLITK 4
#define KCHUNK (NN / SPLITK)
#define BKG 64
#define LDPA 72  // GEMM LDS row stride (64+8 pad), <=2-way conflicts
#define LDP 40   // fallback-otf LDS row stride (32+8 pad)

typedef __bf16 bf16x8 __attribute__((ext_vector_type(8)));
typedef float f32x4 __attribute__((ext_vector_type(4)));
typedef uint16_t u16x8 __attribute__((ext_vector_type(8)));

__device__ __forceinline__ float bf2f(uint16_t u) {
    union { uint32_t u; float f; } c; c.u = ((uint32_t)u) << 16; return c.f;
}
__device__ __forceinline__ uint16_t f2bf(float f) {
    union { float f; uint32_t u; } c; c.f = f;
    uint32_t r = c.u + 0x7fffu + ((c.u >> 16) & 1u);  // RNE
    return (uint16_t)(r >> 16);
}
// wave-uniform dtype probe on x_feature: bf16 storage -> ~all sampled
// exponents in [96,144]; f32 storage -> ~16% (random mantissa halves).
__device__ __forceinline__ bool probe_isbf(const uint16_t* __restrict__ xr) {
    int lane = threadIdx.x & 63;
    uint16_t v = xr[lane * 16];          // even uint16 indices, 2KB span
    int e = (v >> 7) & 0xFF;
    unsigned long long m = __ballot(e >= 96 && e <= 144);
    return __popcll(m) >= 48;
}
__device__ __forceinline__ float combineAt(const void* adj, size_t idx,
                                           bool isbf, float r0, float r1) {
    if (isbf) {
        uint32_t u = ((const uint32_t*)adj)[idx];
        return bf2f((uint16_t)(u & 0xffffu)) * r0 + bf2f((uint16_t)(u >> 16)) * r1;
    } else {
        float2 v = ((const float2*)adj)[idx];
        return v.x * r0 + v.y * r1;
    }
}
// combined value for elements idx, idx+1 (idx must be even)
__device__ __forceinline__ float2 combine2At(const void* adj, size_t idx,
                                             bool isbf, float r0, float r1) {
    if (isbf) {
        uint2 u = ((const uint2*)adj)[idx >> 1];
        return make_float2(
            bf2f((uint16_t)(u.x & 0xffffu)) * r0 + bf2f((uint16_t)(u.x >> 16)) * r1,
            bf2f((uint16_t)(u.y & 0xffffu)) * r0 + bf2f((uint16_t)(u.y >> 16)) * r1);
    } else {
        float4 v = ((const float4*)adj)[idx >> 1];
        return make_float2(v.x * r0 + v.y * r1, v.z * r0 + v.w * r1);
    }
}

// ---- xw0 worker: for thread-index t, compute 8 outputs of
//      xw0T[f][j] = sum_k x[j][k]*w0[k][f] (transposed bf16 store) ----
__device__ __forceinline__ void xw0_work(int t, bool isbf,
        const void* __restrict__ xp, const void* __restrict__ w0p,
        uint16_t* __restrict__ xw0T) {
    int j = t >> 4;
    int f0 = (t & 15) * 8;
    float acc[8] = {0.f,0.f,0.f,0.f,0.f,0.f,0.f,0.f};
    if (isbf) {
        const uint16_t* xrow = (const uint16_t*)xp + (size_t)j * KIN;
        const uint16_t* w0 = (const uint16_t*)w0p;
        for (int k8 = 0; k8 < KIN; k8 += 8) {
            u16x8 xv = *(const u16x8*)(xrow + k8);
            #pragma unroll
            for (int i = 0; i < 8; i++) {
                float a = bf2f(xv[i]);
                u16x8 wv = *(const u16x8*)(w0 + (size_t)(k8 + i) * FOUT + f0);
                #pragma unroll
                for (int q = 0; q < 8; q++) acc[q] += a * bf2f(wv[q]);
            }
        }
    } else {
        const float* xrow = (const float*)xp + (size_t)j * KIN;
        const float* w0 = (const float*)w0p;
        for (int k4 = 0; k4 < KIN; k4 += 4) {
            float4 xv = *(const float4*)(xrow + k4);
            float xa[4] = {xv.x, xv.y, xv.z, xv.w};
            #pragma unroll
            for (int i = 0; i < 4; i++) {
                const float* wr = w0 + (size_t)(k4 + i) * FOUT + f0;
                float4 wa = *(const float4*)wr;
                float4 wb = *(const float4*)(wr + 4);
                acc[0] += xa[i]*wa.x; acc[1] += xa[i]*wa.y;
                acc[2] += xa[i]*wa.z; acc[3] += xa[i]*wa.w;
                acc[4] += xa[i]*wb.x; acc[5] += xa[i]*wb.y;
                acc[6] += xa[i]*wb.z; acc[7] += xa[i]*wb.w;
            }
        }
    }
    #pragma unroll
    for (int q = 0; q < 8; q++) xw0T[(size_t)(f0 + q) * NN + j] = f2bf(acc[q]);
}

// ---- fallback: standalone xw0 ----
__global__ __launch_bounds__(256) void xw0_kernel(
        const void* __restrict__ xp, const void* __restrict__ w0p,
        uint16_t* __restrict__ xw0T) {
    bool isbf = probe_isbf((const uint16_t*)xp);
    xw0_work(blockIdx.x * 256 + threadIdx.x, isbf, xp, w0p, xw0T);
}

// ---- fallback only: h1 = b0, h2 = b1 (otf GEMMs accumulate on top) ----
__global__ __launch_bounds__(256) void init_bias_kernel(
        const uint16_t* __restrict__ xr,
        const void* __restrict__ b0p, const void* __restrict__ b1p,
        float* __restrict__ h1, float* __restrict__ h2) {
    bool isbf = probe_isbf(xr);
    int idx = (blockIdx.x * 256 + threadIdx.x) * 4;
    int f = idx & (FOUT - 1);
    float4 v0, v1;
    if (isbf) {
        const uint16_t* b0 = (const uint16_t*)b0p;
        const uint16_t* b1 = (const uint16_t*)b1p;
        v0 = make_float4(bf2f(b0[f]), bf2f(b0[f+1]), bf2f(b0[f+2]), bf2f(b0[f+3]));
        v1 = make_float4(bf2f(b1[f]), bf2f(b1[f+1]), bf2f(b1[f+2]), bf2f(b1[f+3]));
    } else {
        v0 = *(const float4*)((const float*)b0p + f);
        v1 = *(const float4*)((const float*)b1p + f);
    }
    *(float4*)(h1 + idx) = v0;
    *(float4*)(h2 + idx) = v1;
}

// ---- fat kernel: sym tiles (by<128) + xw0 (by in {128,129}) ----
// sym[i][j] = bf16(adjC[i][j] + adjC[j][i]), paired 64x64 tiles.
__global__ __launch_bounds__(256) void sym_xw0_kernel(
        const uint16_t* __restrict__ xr,
        const void* __restrict__ adj, const void* __restrict__ rwp,
        uint16_t* __restrict__ sym,
        const void* __restrict__ w0p, uint16_t* __restrict__ xw0T) {
    __shared__ float Ds[64][65];
    __shared__ float Es[64][65];
    int I = blockIdx.x, J = blockIdx.y;
    if (J >= 128) {
        // xw0 role: 256 blocks, each covers 2 thread-chunks of the
        // original 131072-thread xw0 sweep.
        bool isbf = probe_isbf(xr);
        int base = (J - 128) * 128 + I;           // 0..255
        xw0_work(base * 512 + threadIdx.x, isbf, xr, w0p, xw0T);
        xw0_work(base * 512 + 256 + threadIdx.x, isbf, xr, w0p, xw0T);
        return;
    }
    if (J < I) return;
    bool isbf = probe_isbf(xr);
    float r0 = isbf ? bf2f(((const uint16_t*)rwp)[0]) : ((const float*)rwp)[0];
    float r1 = isbf ? bf2f(((const uint16_t*)rwp)[1]) : ((const float*)rwp)[1];
    int i0 = I * 64, j0 = J * 64;
    int t = threadIdx.x;
    const bool diag = (I == J);
    #pragma unroll
    for (int s = 0; s < 8; s++) {
        int q = s * 256 + t;
        int a = q >> 5, b2 = (q & 31) * 2;
        float2 d = combine2At(adj, (size_t)(i0 + a) * NN + (j0 + b2), isbf, r0, r1);
        *(float2*)(&Ds[a][b2]) = d;
        if (!diag) {
            float2 e = combine2At(adj, (size_t)(j0 + a) * NN + (i0 + b2), isbf, r0, r1);
            *(float2*)(&Es[a][b2]) = e;
        }
    }
    __syncthreads();
    float (*Ep)[65] = diag ? Ds : Es;
    #pragma unroll
    for (int s = 0; s < 4; s++) {
        int q = s * 256 + t;
        int a = q >> 4, b4 = (q & 15) * 4;
        ushort4 o;
        o.x = f2bf(Ds[a][b4 + 0] + Ep[b4 + 0][a]);
        o.y = f2bf(Ds[a][b4 + 1] + Ep[b4 + 1][a]);
        o.z = f2bf(Ds[a][b4 + 2] + Ep[b4 + 2][a]);
        o.w = f2bf(Ds[a][b4 + 3] + Ep[b4 + 3][a]);
        *(ushort4*)(sym + (size_t)(i0 + a) * NN + (j0 + b4)) = o;
        if (!diag) {
            ushort4 p4;
            p4.x = f2bf(Es[a][b4 + 0] + Ds[b4 + 0][a]);
            p4.y = f2bf(Es[a][b4 + 1] + Ds[b4 + 1][a]);
            p4.z = f2bf(Es[a][b4 + 2] + Ds[b4 + 2][a]);
            p4.w = f2bf(Es[a][b4 + 3] + Ds[b4 + 3][a]);
            *(ushort4*)(sym + (size_t)(j0 + a) * NN + (i0 + b4)) = p4;
        }
    }
}

// ---- fast GEMM: P[kc] tile = sym[m0:m0+64][k-chunk] @ BT^T ----
// m-tile 64, BK 64, grid(128, SPLITK).
__global__ __launch_bounds__(256) void gemm_part_kernel(
        const uint16_t* __restrict__ A, const uint16_t* __restrict__ BT,
        float* __restrict__ P) {
    __shared__ __align__(16) uint16_t As[64 * LDPA];
    __shared__ __align__(16) uint16_t Bs[128 * LDPA];
    const int m0 = blockIdx.x * 64;
    const int k0 = blockIdx.y * KCHUNK;
    const int t = threadIdx.x;
    const int w = t >> 6;
    const int L = t & 63;
    const int nb = w * 32;          // wave's 32-col slice of the 128 cols
    const int fr_l = L & 15;
    const int fr_k = (L >> 4) * 8;
    const int sr = t >> 3;          // 0..31
    const int sk = (t & 7) * 8;     // 0..56

    f32x4 acc[4][2];
    #pragma unroll
    for (int r = 0; r < 4; r++)
        #pragma unroll
        for (int c = 0; c < 2; c++)
            acc[r][c] = (f32x4){0.f, 0.f, 0.f, 0.f};

    for (int kk = 0; kk < KCHUNK; kk += BKG) {
        const int kg = k0 + kk;
        uint4 av0 = *(const uint4*)(A + (size_t)(m0 + sr) * NN + kg + sk);
        uint4 av1 = *(const uint4*)(A + (size_t)(m0 + 32 + sr) * NN + kg + sk);
        uint4 bv0 = *(const uint4*)(BT + (size_t)sr * NN + kg + sk);
        uint4 bv1 = *(const uint4*)(BT + (size_t)(32 + sr) * NN + kg + sk);
        uint4 bv2 = *(const uint4*)(BT + (size_t)(64 + sr) * NN + kg + sk);
        uint4 bv3 = *(const uint4*)(BT + (size_t)(96 + sr) * NN + kg + sk);
        __syncthreads();   // prior iter's fragment reads done
        *(uint4*)(As + sr * LDPA + sk) = av0;
        *(uint4*)(As + (32 + sr) * LDPA + sk) = av1;
        *(uint4*)(Bs + sr * LDPA + sk) = bv0;
        *(uint4*)(Bs + (32 + sr) * LDPA + sk) = bv1;
        *(uint4*)(Bs + (64 + sr) * LDPA + sk) = bv2;
        *(uint4*)(Bs + (96 + sr) * LDPA + sk) = bv3;
        __syncthreads();

        #pragma unroll
        for (int ks = 0; ks < 2; ks++) {
            const int ko = ks * 32 + fr_k;
            bf16x8 af[4], bfv[2];
            #pragma unroll
            for (int r = 0; r < 4; r++)
                af[r] = *(const bf16x8*)(As + (r * 16 + fr_l) * LDPA + ko);
            #pragma unroll
            for (int c = 0; c < 2; c++)
                bfv[c] = *(const bf16x8*)(Bs + (nb + c * 16 + fr_l) * LDPA + ko);
            #pragma unroll
            for (int r = 0; r < 4; r++)
                #pragma unroll
                for (int c = 0; c < 2; c++)
                    acc[r][c] = __builtin_amdgcn_mfma_f32_16x16x32_bf16(af[r], bfv[c], acc[r][c], 0, 0, 0);
        }
    }

    float* part = P + (size_t)blockIdx.y * NN * FOUT;
    #pragma unroll
    for (int r = 0; r < 4; r++)
        #pragma unroll
        for (int c = 0; c < 2; c++) {
            int col = nb + c * 16 + fr_l;
            int rowb = m0 + r * 16 + (L >> 4) * 4;
            #pragma unroll
            for (int q = 0; q < 4; q++)
                part[(size_t)(rowb + q) * FOUT + col] = acc[r][c][q];
        }
}

// ---- fallback GEMM: stages sym tile on the fly from raw adj (atomics) ----
__global__ __launch_bounds__(256) void gemm_otf_kernel(
        const uint16_t* __restrict__ xr,
        const void* __restrict__ adj, const uint16_t* __restrict__ BT,
        float* __restrict__ out, const void* __restrict__ rwp) {
    bool isbf = probe_isbf(xr);
    float r0 = isbf ? bf2f(((const uint16_t*)rwp)[0]) : ((const float*)rwp)[0];
    float r1 = isbf ? bf2f(((const uint16_t*)rwp)[1]) : ((const float*)rwp)[1];
    __shared__ __align__(16) uint16_t As[128 * LDP];
    __shared__ __align__(16) uint16_t Bs[128 * LDP];
    const int m0 = blockIdx.x * 128;
    const int k0 = blockIdx.y * KCHUNK;
    const int t = threadIdx.x;
    const int w = t >> 6;
    const int L = t & 63;
    const int mb = (w & 1) * 64;
    const int nb = (w >> 1) * 64;
    const int fr_l = L & 15;
    const int fr_k = (L >> 4) * 8;
    const int sr = t >> 2;
    const int sk = (t & 3) * 8;

    f32x4 acc[4][4];
    #pragma unroll
    for (int r = 0; r < 4; r++)
        #pragma unroll
        for (int c = 0; c < 4; c++)
            acc[r][c] = (f32x4){0.f, 0.f, 0.f, 0.f};

    for (int kk = 0; kk < KCHUNK; kk += 32) {
        const int kg = k0 + kk;
        uint4 bv0 = *(const uint4*)(BT + (size_t)sr * NN + kg + sk);
        uint4 bv1 = *(const uint4*)(BT + (size_t)(64 + sr) * NN + kg + sk);
        __syncthreads();   // prior iter's fragment reads done
        *(uint4*)(Bs + sr * LDP + sk) = bv0;
        *(uint4*)(Bs + (64 + sr) * LDP + sk) = bv1;
        #pragma unroll
        for (int s = 0; s < 16; s++) {
            int idx = s * 256 + t;
            int m = idx >> 5, k = idx & 31;
            As[m * LDP + k] = f2bf(combineAt(adj, (size_t)(m0 + m) * NN + (kg + k), isbf, r0, r1));
        }
        __syncthreads();   // pass1 visible
        #pragma unroll
        for (int s = 0; s < 16; s++) {
            int idx = s * 256 + t;
            int k = idx >> 7, m = idx & 127;
            float v2 = combineAt(adj, (size_t)(kg + k) * NN + (m0 + m), isbf, r0, r1);
            As[m * LDP + k] = f2bf(bf2f(As[m * LDP + k]) + v2);
        }
        __syncthreads();   // staging complete

        bf16x8 af[4], bf[4];
        #pragma unroll
        for (int r = 0; r < 4; r++)
            af[r] = *(const bf16x8*)(As + (mb + r * 16 + fr_l) * LDP + fr_k);
        #pragma unroll
        for (int c = 0; c < 4; c++)
            bf[c] = *(const bf16x8*)(Bs + (nb + c * 16 + fr_l) * LDP + fr_k);
        #pragma unroll
        for (int r = 0; r < 4; r++)
            #pragma unroll
            for (int c = 0; c < 4; c++)
                acc[r][c] = __builtin_amdgcn_mfma_f32_16x16x32_bf16(af[r], bf[c], acc[r][c], 0, 0, 0);
    }

    #pragma unroll
    for (int r = 0; r < 4; r++)
        #pragma unroll
        for (int c = 0; c < 4; c++) {
            int col = nb + c * 16 + (L & 15);
            int rowb = m0 + mb + r * 16 + (L >> 4) * 4;
            #pragma unroll
            for (int q = 0; q < 4; q++)
                atomicAdd(out + (size_t)(rowb + q) * FOUT + col, acc[r][c][q]);
        }
}

// ---- reduce1: h1 = sum_p P[p] + b0;  hwT[f][j] = sum_k h1[j][k]*w1[k][f] ----
__global__ __launch_bounds__(256) void reduce1_kernel(
        const uint16_t* __restrict__ xr,
        const float* __restrict__ P, const void* __restrict__ b0p,
        const void* __restrict__ w1p, float* __restrict__ h1,
        uint16_t* __restrict__ hwT) {
    bool isbf = probe_isbf(xr);
    __shared__ float hs[16][132];
    const int t = threadIdx.x;
    const int jr = t >> 4;
    const int f0 = (t & 15) * 8;
    const int j = blockIdx.x * 16 + jr;
    // phase 1: reduce SPLITK partials + bias -> h1 row slice
    f32x4 s0 = (f32x4){0.f,0.f,0.f,0.f}, s1 = (f32x4){0.f,0.f,0.f,0.f};
    const float* Pj = P + (size_t)j * FOUT + f0;
    #pragma unroll
    for (int p = 0; p < SPLITK; p++) {
        const float* pp = Pj + (size_t)p * NN * FOUT;
        s0 += *(const f32x4*)pp;
        s1 += *(const f32x4*)(pp + 4);
    }
    if (isbf) {
        const uint16_t* b0 = (const uint16_t*)b0p;
        #pragma unroll
        for (int q = 0; q < 4; q++) { s0[q] += bf2f(b0[f0+q]); s1[q] += bf2f(b0[f0+4+q]); }
    } else {
        const float* b0 = (const float*)b0p;
        s0 += *(const f32x4*)(b0 + f0);
        s1 += *(const f32x4*)(b0 + f0 + 4);
    }
    *(f32x4*)(h1 + (size_t)j * FOUT + f0) = s0;
    *(f32x4*)(h1 + (size_t)j * FOUT + f0 + 4) = s1;
    *(f32x4*)(&hs[jr][f0]) = s0;
    *(f32x4*)(&hs[jr][f0 + 4]) = s1;
    __syncthreads();
    // phase 2: hwT[f0+q][j] = sum_k hs[jr][k] * w1[k][f0+q]
    float acc[8] = {0.f,0.f,0.f,0.f,0.f,0.f,0.f,0.f};
    if (isbf) {
        const uint16_t* w1 = (const uint16_t*)w1p;
        for (int k4 = 0; k4 < FOUT; k4 += 4) {
            f32x4 a4 = *(const f32x4*)(&hs[jr][k4]);
            #pragma unroll
            for (int i = 0; i < 4; i++) {
                u16x8 wv = *(const u16x8*)(w1 + (size_t)(k4 + i) * FOUT + f0);
                #pragma unroll
                for (int q = 0; q < 8; q++) acc[q] += a4[i] * bf2f(wv[q]);
            }
        }
    } else {
        const float* w1 = (const float*)w1p;
        for (int k4 = 0; k4 < FOUT; k4 += 4) {
            f32x4 a4 = *(const f32x4*)(&hs[jr][k4]);
            #pragma unroll
            for (int i = 0; i < 4; i++) {
                const float* wr = w1 + (size_t)(k4 + i) * FOUT + f0;
                f32x4 wa = *(const f32x4*)wr;
                f32x4 wb = *(const f32x4*)(wr + 4);
                #pragma unroll
                for (int q = 0; q < 4; q++) { acc[q] += a4[i]*wa[q]; acc[4+q] += a4[i]*wb[q]; }
            }
        }
    }
    #pragma unroll
    for (int q = 0; q < 8; q++) hwT[(size_t)(f0 + q) * NN + j] = f2bf(acc[q]);
}

// ---- reduce2: out = 0.5*(h1 + (sum_p P[p] + b1)), dtype per probe ----
__global__ __launch_bounds__(256) void reduce2_kernel(
        const uint16_t* __restrict__ xr,
        const float* __restrict__ P, const void* __restrict__ b1p,
        const float* __restrict__ h1, void* __restrict__ outp) {
    bool isbf = probe_isbf(xr);
    int idx = (blockIdx.x * 256 + threadIdx.x) * 4;
    int f = idx & (FOUT - 1);
    f32x4 s = (f32x4){0.f,0.f,0.f,0.f};
    #pragma unroll
    for (int p = 0; p < SPLITK; p++)
        s += *(const f32x4*)(P + (size_t)p * NN * FOUT + idx);
    if (isbf) {
        const uint16_t* b1 = (const uint16_t*)b1p;
        #pragma unroll
        for (int q = 0; q < 4; q++) s[q] += bf2f(b1[f + q]);
    } else {
        s += *(const f32x4*)((const float*)b1p + f);
    }
    f32x4 h = *(const f32x4*)(h1 + idx);
    f32x4 r = 0.5f * (h + s);
    if (isbf) {
        ushort4 ov = make_ushort4(f2bf(r[0]), f2bf(r[1]), f2bf(r[2]), f2bf(r[3]));
        *(ushort4*)((uint16_t*)outp + idx) = ov;
    } else {
        *(f32x4*)((float*)outp + idx) = r;
    }
}

// ---- fallback: hwT[f][j] = sum_k h1[j][k]*w1[k][f] ----
__global__ __launch_bounds__(256) void h1w1_kernel(
        const uint16_t* __restrict__ xr,
        const float* __restrict__ h1, const void* __restrict__ w1p,
        uint16_t* __restrict__ hwT) {
    bool isbf = probe_isbf(xr);
    int t = blockIdx.x * 256 + threadIdx.x;
    int j = t >> 4;
    int f0 = (t & 15) * 8;
    float acc[8] = {0.f,0.f,0.f,0.f,0.f,0.f,0.f,0.f};
    const float* hrow = h1 + (size_t)j * FOUT;
    if (isbf) {
        const uint16_t* w1 = (const uint16_t*)w1p;
        for (int k4 = 0; k4 < FOUT; k4 += 4) {
            float4 a4 = *(const float4*)(hrow + k4);
            float av[4] = {a4.x, a4.y, a4.z, a4.w};
            #pragma unroll
            for (int i = 0; i < 4; i++) {
                u16x8 wv = *(const u16x8*)(w1 + (size_t)(k4 + i) * FOUT + f0);
                #pragma unroll
                for (int q = 0; q < 8; q++) acc[q] += av[i] * bf2f(wv[q]);
            }
        }
    } else {
        const float* w1 = (const float*)w1p;
        for (int k4 = 0; k4 < FOUT; k4 += 4) {
            float4 a4 = *(const float4*)(hrow + k4);
            float av[4] = {a4.x, a4.y, a4.z, a4.w};
            #pragma unroll
            for (int i = 0; i < 4; i++) {
                const float* wr = w1 + (size_t)(k4 + i) * FOUT + f0;
                float4 wa = *(const float4*)wr;
                float4 wb = *(const float4*)(wr + 4);
                acc[0] += av[i]*wa.x; acc[1] += av[i]*wa.y;
                acc[2] += av[i]*wa.z; acc[3] += av[i]*wa.w;
                acc[4] += av[i]*wb.x; acc[5] += av[i]*wb.y;
                acc[6] += av[i]*wb.z; acc[7] += av[i]*wb.w;
            }
        }
    }
    #pragma unroll
    for (int q = 0; q < 8; q++) hwT[(size_t)(f0 + q) * NN + j] = f2bf(acc[q]);
}

// ---- fallback: out = 0.5*(h1+h2), dtype per probe ----
__global__ __launch_bounds__(256) void final_kernel(
        const uint16_t* __restrict__ xr,
        const float* __restrict__ h1, const float* __restrict__ h2,
        void* __restrict__ outp) {
    bool isbf = probe_isbf(xr);
    int idx = (blockIdx.x * 256 + threadIdx.x) * 4;
    float4 a = *(const float4*)(h1 + idx);
    float4 b = *(const float4*)(h2 + idx);
    float4 r = make_float4(0.5f*(a.x+b.x), 0.5f*(a.y+b.y), 0.5f*(a.z+b.z), 0.5f*(a.w+b.w));
    if (isbf) {
        ushort4 ov = make_ushort4(f2bf(r.x), f2bf(r.y), f2bf(r.z), f2bf(r.w));
        *(ushort4*)((uint16_t*)outp + idx) = ov;
    } else {
        *(float4*)((float*)outp + idx) = r;
    }
}

extern "C" void kernel_launch(void* const* d_in, const int* in_sizes, int n_in,
                              void* d_out, int out_size, void* d_ws, size_t ws_size,
                              hipStream_t stream) {
    char* ws = (char*)d_ws;
    uint16_t* xw0T = (uint16_t*)(ws);
    uint16_t* hwT  = (uint16_t*)(ws + (2u << 20));
    float*    h1   = (float*)   (ws + (4u << 20));
    float*    h2   = (float*)   (ws + (8u << 20));
    uint16_t* sym  = (uint16_t*)(ws + (13u << 20));
    float*    P    = (float*)   (ws + ((size_t)144 << 20));
    const uint16_t* xr = (const uint16_t*)d_in[0];
    // P ends at 144MB + SPLITK*8192*128*4 = ~160.8MB
    const size_t need_fast = ((size_t)144 << 20)
                           + (size_t)SPLITK * NN * FOUT * 4 + (1u << 20);
    const bool fast = ws_size >= need_fast;

    if (fast) {
        sym_xw0_kernel<<<dim3(128, 130), 256, 0, stream>>>(
            xr, d_in[1], d_in[6], sym, d_in[2], xw0T);
        gemm_part_kernel<<<dim3(128, SPLITK), 256, 0, stream>>>(sym, xw0T, P);
        reduce1_kernel<<<512, 256, 0, stream>>>(xr, P, d_in[3], d_in[4], h1, hwT);
        gemm_part_kernel<<<dim3(128, SPLITK), 256, 0, stream>>>(sym, hwT, P);
        reduce2_kernel<<<1024, 256, 0, stream>>>(xr, P, d_in[5], h1, d_out);
    } else {
        xw0_kernel<<<512, 256, 0, stream>>>(d_in[0], d_in[2], xw0T);
        init_bias_kernel<<<1024, 256, 0, stream>>>(xr, d_in[3], d_in[5], h1, h2);
        gemm_otf_kernel<<<dim3(64, SPLITK), 256, 0, stream>>>(xr, d_in[1], xw0T, h1, d_in[6]);
        h1w1_kernel<<<512, 256, 0, stream>>>(xr, h1, d_in[4], hwT);
        gemm_otf_kernel<<<dim3(64, SPLITK), 256, 0, stream>>>(xr, d_in[1], hwT, h2, d_in[6]);
        final_kernel<<<1024, 256, 0, stream>>>(xr, h1, h2, d_out);
    }
}

// Round 4
// 883.535 us; speedup vs baseline: 1.0319x; 1.0319x over previous
//
#include <hip/hip_runtime.h>
#include <stdint.h>

// MHGCN: out = 0.5*(h1+h2); h1 = sym@(x@w0)+b0; h2 = sym@(h1@w1)+b1
// sym = (adj·rw) + (adj·rw)^T. N=8192, IN_F=256, OUT_F=128, R=2.
// Round 7: revert R3's fat sym+xw0 merge (regressed). Keep SPLITK=4
// (halved P traffic) but retile GEMM to m-tile 32 so grid stays at
// 1024 blocks (4 blocks/CU, R2's proven occupancy). Triangular-packed
// sym grid (cyclic-diagonal mapping, no dead J<I dispatches).
//
// ws layout (fast path):
//   [0,2MB)      xw0T  bf16 [128][8192]
//   [2,4MB)      hwT   bf16 [128][8192]
//   [4,8MB)      h1    f32  [8192][128]
//   [8,12MB)     h2    f32  (fallback path only)
//   [13,141MB)   sym   bf16 [8192][8192]
//   [144,160MB)  P     f32  [SPLITK][8192][128] partials

#define NN 8192
#define KIN 256
#define FOUT 128
#define SPLITK 4
#define KCHUNK (NN / SPLITK)
#define BKG 64
#define LDPA 72  // GEMM LDS row stride (64+8 pad), <=2-way conflicts
#define LDP 40   // fallback-otf LDS row stride (32+8 pad)

typedef __bf16 bf16x8 __attribute__((ext_vector_type(8)));
typedef float f32x4 __attribute__((ext_vector_type(4)));
typedef uint16_t u16x8 __attribute__((ext_vector_type(8)));

__device__ __forceinline__ float bf2f(uint16_t u) {
    union { uint32_t u; float f; } c; c.u = ((uint32_t)u) << 16; return c.f;
}
__device__ __forceinline__ uint16_t f2bf(float f) {
    union { float f; uint32_t u; } c; c.f = f;
    uint32_t r = c.u + 0x7fffu + ((c.u >> 16) & 1u);  // RNE
    return (uint16_t)(r >> 16);
}
// wave-uniform dtype probe on x_feature: bf16 storage -> ~all sampled
// exponents in [96,144]; f32 storage -> ~16% (random mantissa halves).
__device__ __forceinline__ bool probe_isbf(const uint16_t* __restrict__ xr) {
    int lane = threadIdx.x & 63;
    uint16_t v = xr[lane * 16];          // even uint16 indices, 2KB span
    int e = (v >> 7) & 0xFF;
    unsigned long long m = __ballot(e >= 96 && e <= 144);
    return __popcll(m) >= 48;
}
__device__ __forceinline__ float combineAt(const void* adj, size_t idx,
                                           bool isbf, float r0, float r1) {
    if (isbf) {
        uint32_t u = ((const uint32_t*)adj)[idx];
        return bf2f((uint16_t)(u & 0xffffu)) * r0 + bf2f((uint16_t)(u >> 16)) * r1;
    } else {
        float2 v = ((const float2*)adj)[idx];
        return v.x * r0 + v.y * r1;
    }
}
// combined value for elements idx, idx+1 (idx must be even)
__device__ __forceinline__ float2 combine2At(const void* adj, size_t idx,
                                             bool isbf, float r0, float r1) {
    if (isbf) {
        uint2 u = ((const uint2*)adj)[idx >> 1];
        return make_float2(
            bf2f((uint16_t)(u.x & 0xffffu)) * r0 + bf2f((uint16_t)(u.x >> 16)) * r1,
            bf2f((uint16_t)(u.y & 0xffffu)) * r0 + bf2f((uint16_t)(u.y >> 16)) * r1);
    } else {
        float4 v = ((const float4*)adj)[idx >> 1];
        return make_float2(v.x * r0 + v.y * r1, v.z * r0 + v.w * r1);
    }
}

// ---- xw0T[f][j] = sum_k x[j][k]*w0[k][f], store transposed bf16 ----
__global__ __launch_bounds__(256) void xw0_kernel(
        const void* __restrict__ xp, const void* __restrict__ w0p,
        uint16_t* __restrict__ xw0T) {
    bool isbf = probe_isbf((const uint16_t*)xp);
    int t = blockIdx.x * 256 + threadIdx.x;   // 131072 threads
    int j = t >> 4;
    int f0 = (t & 15) * 8;
    float acc[8] = {0.f,0.f,0.f,0.f,0.f,0.f,0.f,0.f};
    if (isbf) {
        const uint16_t* xrow = (const uint16_t*)xp + (size_t)j * KIN;
        const uint16_t* w0 = (const uint16_t*)w0p;
        for (int k8 = 0; k8 < KIN; k8 += 8) {
            u16x8 xv = *(const u16x8*)(xrow + k8);
            #pragma unroll
            for (int i = 0; i < 8; i++) {
                float a = bf2f(xv[i]);
                u16x8 wv = *(const u16x8*)(w0 + (size_t)(k8 + i) * FOUT + f0);
                #pragma unroll
                for (int q = 0; q < 8; q++) acc[q] += a * bf2f(wv[q]);
            }
        }
    } else {
        const float* xrow = (const float*)xp + (size_t)j * KIN;
        const float* w0 = (const float*)w0p;
        for (int k4 = 0; k4 < KIN; k4 += 4) {
            float4 xv = *(const float4*)(xrow + k4);
            float xa[4] = {xv.x, xv.y, xv.z, xv.w};
            #pragma unroll
            for (int i = 0; i < 4; i++) {
                const float* wr = w0 + (size_t)(k4 + i) * FOUT + f0;
                float4 wa = *(const float4*)wr;
                float4 wb = *(const float4*)(wr + 4);
                acc[0] += xa[i]*wa.x; acc[1] += xa[i]*wa.y;
                acc[2] += xa[i]*wa.z; acc[3] += xa[i]*wa.w;
                acc[4] += xa[i]*wb.x; acc[5] += xa[i]*wb.y;
                acc[6] += xa[i]*wb.z; acc[7] += xa[i]*wb.w;
            }
        }
    }
    #pragma unroll
    for (int q = 0; q < 8; q++) xw0T[(size_t)(f0 + q) * NN + j] = f2bf(acc[q]);
}

// ---- fallback only: h1 = b0, h2 = b1 (otf GEMMs accumulate on top) ----
__global__ __launch_bounds__(256) void init_bias_kernel(
        const uint16_t* __restrict__ xr,
        const void* __restrict__ b0p, const void* __restrict__ b1p,
        float* __restrict__ h1, float* __restrict__ h2) {
    bool isbf = probe_isbf(xr);
    int idx = (blockIdx.x * 256 + threadIdx.x) * 4;
    int f = idx & (FOUT - 1);
    float4 v0, v1;
    if (isbf) {
        const uint16_t* b0 = (const uint16_t*)b0p;
        const uint16_t* b1 = (const uint16_t*)b1p;
        v0 = make_float4(bf2f(b0[f]), bf2f(b0[f+1]), bf2f(b0[f+2]), bf2f(b0[f+3]));
        v1 = make_float4(bf2f(b1[f]), bf2f(b1[f+1]), bf2f(b1[f+2]), bf2f(b1[f+3]));
    } else {
        v0 = *(const float4*)((const float*)b0p + f);
        v1 = *(const float4*)((const float*)b1p + f);
    }
    *(float4*)(h1 + idx) = v0;
    *(float4*)(h2 + idx) = v1;
}

// ---- sym: paired 64x64 tiles, triangular-packed cyclic grid ----
// grid (128, 65): by==0 -> diagonal; by in 1..63 -> pair (bx,(bx+by)&127)
// each unordered pair once; by==64 valid only for bx<64 (antipodal pairs).
__global__ __launch_bounds__(256) void sym_kernel(
        const uint16_t* __restrict__ xr,
        const void* __restrict__ adj, const void* __restrict__ rwp,
        uint16_t* __restrict__ sym) {
    int bx = blockIdx.x, by = blockIdx.y;
    if (by == 64 && bx >= 64) return;
    int I = bx, J = (bx + by) & 127;
    bool isbf = probe_isbf(xr);
    float r0 = isbf ? bf2f(((const uint16_t*)rwp)[0]) : ((const float*)rwp)[0];
    float r1 = isbf ? bf2f(((const uint16_t*)rwp)[1]) : ((const float*)rwp)[1];
    __shared__ float Ds[64][65];
    __shared__ float Es[64][65];
    int i0 = I * 64, j0 = J * 64;
    int t = threadIdx.x;
    const bool diag = (I == J);
    #pragma unroll
    for (int s = 0; s < 8; s++) {
        int q = s * 256 + t;
        int a = q >> 5, b2 = (q & 31) * 2;
        float2 d = combine2At(adj, (size_t)(i0 + a) * NN + (j0 + b2), isbf, r0, r1);
        *(float2*)(&Ds[a][b2]) = d;
        if (!diag) {
            float2 e = combine2At(adj, (size_t)(j0 + a) * NN + (i0 + b2), isbf, r0, r1);
            *(float2*)(&Es[a][b2]) = e;
        }
    }
    __syncthreads();
    float (*Ep)[65] = diag ? Ds : Es;
    #pragma unroll
    for (int s = 0; s < 4; s++) {
        int q = s * 256 + t;
        int a = q >> 4, b4 = (q & 15) * 4;
        ushort4 o;
        o.x = f2bf(Ds[a][b4 + 0] + Ep[b4 + 0][a]);
        o.y = f2bf(Ds[a][b4 + 1] + Ep[b4 + 1][a]);
        o.z = f2bf(Ds[a][b4 + 2] + Ep[b4 + 2][a]);
        o.w = f2bf(Ds[a][b4 + 3] + Ep[b4 + 3][a]);
        *(ushort4*)(sym + (size_t)(i0 + a) * NN + (j0 + b4)) = o;
        if (!diag) {
            ushort4 p4;
            p4.x = f2bf(Es[a][b4 + 0] + Ds[b4 + 0][a]);
            p4.y = f2bf(Es[a][b4 + 1] + Ds[b4 + 1][a]);
            p4.z = f2bf(Es[a][b4 + 2] + Ds[b4 + 2][a]);
            p4.w = f2bf(Es[a][b4 + 3] + Ds[b4 + 3][a]);
            *(ushort4*)(sym + (size_t)(j0 + a) * NN + (i0 + b4)) = p4;
        }
    }
}

// ---- fast GEMM: P[kc] tile = sym[m0:m0+32][k-chunk] @ BT^T ----
// m-tile 32, BK 64, grid(256, SPLITK) = 1024 blocks -> 4 blocks/CU.
__global__ __launch_bounds__(256) void gemm_part_kernel(
        const uint16_t* __restrict__ A, const uint16_t* __restrict__ BT,
        float* __restrict__ P) {
    __shared__ __align__(16) uint16_t As[32 * LDPA];
    __shared__ __align__(16) uint16_t Bs[128 * LDPA];
    const int m0 = blockIdx.x * 32;
    const int k0 = blockIdx.y * KCHUNK;
    const int t = threadIdx.x;
    const int w = t >> 6;
    const int L = t & 63;
    const int nb = w * 32;          // wave's 32-col slice of the 128 cols
    const int fr_l = L & 15;
    const int fr_k = (L >> 4) * 8;
    const int sr = t >> 3;          // 0..31
    const int sk = (t & 7) * 8;     // 0..56

    f32x4 acc[2][2];
    #pragma unroll
    for (int r = 0; r < 2; r++)
        #pragma unroll
        for (int c = 0; c < 2; c++)
            acc[r][c] = (f32x4){0.f, 0.f, 0.f, 0.f};

    for (int kk = 0; kk < KCHUNK; kk += BKG) {
        const int kg = k0 + kk;
        uint4 av0 = *(const uint4*)(A + (size_t)(m0 + sr) * NN + kg + sk);
        uint4 bv0 = *(const uint4*)(BT + (size_t)sr * NN + kg + sk);
        uint4 bv1 = *(const uint4*)(BT + (size_t)(32 + sr) * NN + kg + sk);
        uint4 bv2 = *(const uint4*)(BT + (size_t)(64 + sr) * NN + kg + sk);
        uint4 bv3 = *(const uint4*)(BT + (size_t)(96 + sr) * NN + kg + sk);
        __syncthreads();   // prior iter's fragment reads done
        *(uint4*)(As + sr * LDPA + sk) = av0;
        *(uint4*)(Bs + sr * LDPA + sk) = bv0;
        *(uint4*)(Bs + (32 + sr) * LDPA + sk) = bv1;
        *(uint4*)(Bs + (64 + sr) * LDPA + sk) = bv2;
        *(uint4*)(Bs + (96 + sr) * LDPA + sk) = bv3;
        __syncthreads();

        #pragma unroll
        for (int ks = 0; ks < 2; ks++) {
            const int ko = ks * 32 + fr_k;
            bf16x8 af[2], bfv[2];
            #pragma unroll
            for (int r = 0; r < 2; r++)
                af[r] = *(const bf16x8*)(As + (r * 16 + fr_l) * LDPA + ko);
            #pragma unroll
            for (int c = 0; c < 2; c++)
                bfv[c] = *(const bf16x8*)(Bs + (nb + c * 16 + fr_l) * LDPA + ko);
            #pragma unroll
            for (int r = 0; r < 2; r++)
                #pragma unroll
                for (int c = 0; c < 2; c++)
                    acc[r][c] = __builtin_amdgcn_mfma_f32_16x16x32_bf16(af[r], bfv[c], acc[r][c], 0, 0, 0);
        }
    }

    float* part = P + (size_t)blockIdx.y * NN * FOUT;
    #pragma unroll
    for (int r = 0; r < 2; r++)
        #pragma unroll
        for (int c = 0; c < 2; c++) {
            int col = nb + c * 16 + fr_l;
            int rowb = m0 + r * 16 + (L >> 4) * 4;
            #pragma unroll
            for (int q = 0; q < 4; q++)
                part[(size_t)(rowb + q) * FOUT + col] = acc[r][c][q];
        }
}

// ---- fallback GEMM: stages sym tile on the fly from raw adj (atomics) ----
__global__ __launch_bounds__(256) void gemm_otf_kernel(
        const uint16_t* __restrict__ xr,
        const void* __restrict__ adj, const uint16_t* __restrict__ BT,
        float* __restrict__ out, const void* __restrict__ rwp) {
    bool isbf = probe_isbf(xr);
    float r0 = isbf ? bf2f(((const uint16_t*)rwp)[0]) : ((const float*)rwp)[0];
    float r1 = isbf ? bf2f(((const uint16_t*)rwp)[1]) : ((const float*)rwp)[1];
    __shared__ __align__(16) uint16_t As[128 * LDP];
    __shared__ __align__(16) uint16_t Bs[128 * LDP];
    const int m0 = blockIdx.x * 128;
    const int k0 = blockIdx.y * KCHUNK;
    const int t = threadIdx.x;
    const int w = t >> 6;
    const int L = t & 63;
    const int mb = (w & 1) * 64;
    const int nb = (w >> 1) * 64;
    const int fr_l = L & 15;
    const int fr_k = (L >> 4) * 8;
    const int sr = t >> 2;
    const int sk = (t & 3) * 8;

    f32x4 acc[4][4];
    #pragma unroll
    for (int r = 0; r < 4; r++)
        #pragma unroll
        for (int c = 0; c < 4; c++)
            acc[r][c] = (f32x4){0.f, 0.f, 0.f, 0.f};

    for (int kk = 0; kk < KCHUNK; kk += 32) {
        const int kg = k0 + kk;
        uint4 bv0 = *(const uint4*)(BT + (size_t)sr * NN + kg + sk);
        uint4 bv1 = *(const uint4*)(BT + (size_t)(64 + sr) * NN + kg + sk);
        __syncthreads();   // prior iter's fragment reads done
        *(uint4*)(Bs + sr * LDP + sk) = bv0;
        *(uint4*)(Bs + (64 + sr) * LDP + sk) = bv1;
        #pragma unroll
        for (int s = 0; s < 16; s++) {
            int idx = s * 256 + t;
            int m = idx >> 5, k = idx & 31;
            As[m * LDP + k] = f2bf(combineAt(adj, (size_t)(m0 + m) * NN + (kg + k), isbf, r0, r1));
        }
        __syncthreads();   // pass1 visible
        #pragma unroll
        for (int s = 0; s < 16; s++) {
            int idx = s * 256 + t;
            int k = idx >> 7, m = idx & 127;
            float v2 = combineAt(adj, (size_t)(kg + k) * NN + (m0 + m), isbf, r0, r1);
            As[m * LDP + k] = f2bf(bf2f(As[m * LDP + k]) + v2);
        }
        __syncthreads();   // staging complete

        bf16x8 af[4], bf[4];
        #pragma unroll
        for (int r = 0; r < 4; r++)
            af[r] = *(const bf16x8*)(As + (mb + r * 16 + fr_l) * LDP + fr_k);
        #pragma unroll
        for (int c = 0; c < 4; c++)
            bf[c] = *(const bf16x8*)(Bs + (nb + c * 16 + fr_l) * LDP + fr_k);
        #pragma unroll
        for (int r = 0; r < 4; r++)
            #pragma unroll
            for (int c = 0; c < 4; c++)
                acc[r][c] = __builtin_amdgcn_mfma_f32_16x16x32_bf16(af[r], bf[c], acc[r][c], 0, 0, 0);
    }

    #pragma unroll
    for (int r = 0; r < 4; r++)
        #pragma unroll
        for (int c = 0; c < 4; c++) {
            int col = nb + c * 16 + (L & 15);
            int rowb = m0 + mb + r * 16 + (L >> 4) * 4;
            #pragma unroll
            for (int q = 0; q < 4; q++)
                atomicAdd(out + (size_t)(rowb + q) * FOUT + col, acc[r][c][q]);
        }
}

// ---- reduce1: h1 = sum_p P[p] + b0;  hwT[f][j] = sum_k h1[j][k]*w1[k][f] ----
__global__ __launch_bounds__(256) void reduce1_kernel(
        const uint16_t* __restrict__ xr,
        const float* __restrict__ P, const void* __restrict__ b0p,
        const void* __restrict__ w1p, float* __restrict__ h1,
        uint16_t* __restrict__ hwT) {
    bool isbf = probe_isbf(xr);
    __shared__ float hs[16][132];
    const int t = threadIdx.x;
    const int jr = t >> 4;
    const int f0 = (t & 15) * 8;
    const int j = blockIdx.x * 16 + jr;
    // phase 1: reduce SPLITK partials + bias -> h1 row slice
    f32x4 s0 = (f32x4){0.f,0.f,0.f,0.f}, s1 = (f32x4){0.f,0.f,0.f,0.f};
    const float* Pj = P + (size_t)j * FOUT + f0;
    #pragma unroll
    for (int p = 0; p < SPLITK; p++) {
        const float* pp = Pj + (size_t)p * NN * FOUT;
        s0 += *(const f32x4*)pp;
        s1 += *(const f32x4*)(pp + 4);
    }
    if (isbf) {
        const uint16_t* b0 = (const uint16_t*)b0p;
        #pragma unroll
        for (int q = 0; q < 4; q++) { s0[q] += bf2f(b0[f0+q]); s1[q] += bf2f(b0[f0+4+q]); }
    } else {
        const float* b0 = (const float*)b0p;
        s0 += *(const f32x4*)(b0 + f0);
        s1 += *(const f32x4*)(b0 + f0 + 4);
    }
    *(f32x4*)(h1 + (size_t)j * FOUT + f0) = s0;
    *(f32x4*)(h1 + (size_t)j * FOUT + f0 + 4) = s1;
    *(f32x4*)(&hs[jr][f0]) = s0;
    *(f32x4*)(&hs[jr][f0 + 4]) = s1;
    __syncthreads();
    // phase 2: hwT[f0+q][j] = sum_k hs[jr][k] * w1[k][f0+q]
    float acc[8] = {0.f,0.f,0.f,0.f,0.f,0.f,0.f,0.f};
    if (isbf) {
        const uint16_t* w1 = (const uint16_t*)w1p;
        for (int k4 = 0; k4 < FOUT; k4 += 4) {
            f32x4 a4 = *(const f32x4*)(&hs[jr][k4]);
            #pragma unroll
            for (int i = 0; i < 4; i++) {
                u16x8 wv = *(const u16x8*)(w1 + (size_t)(k4 + i) * FOUT + f0);
                #pragma unroll
                for (int q = 0; q < 8; q++) acc[q] += a4[i] * bf2f(wv[q]);
            }
        }
    } else {
        const float* w1 = (const float*)w1p;
        for (int k4 = 0; k4 < FOUT; k4 += 4) {
            f32x4 a4 = *(const f32x4*)(&hs[jr][k4]);
            #pragma unroll
            for (int i = 0; i < 4; i++) {
                const float* wr = w1 + (size_t)(k4 + i) * FOUT + f0;
                f32x4 wa = *(const f32x4*)wr;
                f32x4 wb = *(const f32x4*)(wr + 4);
                #pragma unroll
                for (int q = 0; q < 4; q++) { acc[q] += a4[i]*wa[q]; acc[4+q] += a4[i]*wb[q]; }
            }
        }
    }
    #pragma unroll
    for (int q = 0; q < 8; q++) hwT[(size_t)(f0 + q) * NN + j] = f2bf(acc[q]);
}

// ---- reduce2: out = 0.5*(h1 + (sum_p P[p] + b1)), dtype per probe ----
__global__ __launch_bounds__(256) void reduce2_kernel(
        const uint16_t* __restrict__ xr,
        const float* __restrict__ P, const void* __restrict__ b1p,
        const float* __restrict__ h1, void* __restrict__ outp) {
    bool isbf = probe_isbf(xr);
    int idx = (blockIdx.x * 256 + threadIdx.x) * 4;
    int f = idx & (FOUT - 1);
    f32x4 s = (f32x4){0.f,0.f,0.f,0.f};
    #pragma unroll
    for (int p = 0; p < SPLITK; p++)
        s += *(const f32x4*)(P + (size_t)p * NN * FOUT + idx);
    if (isbf) {
        const uint16_t* b1 = (const uint16_t*)b1p;
        #pragma unroll
        for (int q = 0; q < 4; q++) s[q] += bf2f(b1[f + q]);
    } else {
        s += *(const f32x4*)((const float*)b1p + f);
    }
    f32x4 h = *(const f32x4*)(h1 + idx);
    f32x4 r = 0.5f * (h + s);
    if (isbf) {
        ushort4 ov = make_ushort4(f2bf(r[0]), f2bf(r[1]), f2bf(r[2]), f2bf(r[3]));
        *(ushort4*)((uint16_t*)outp + idx) = ov;
    } else {
        *(f32x4*)((float*)outp + idx) = r;
    }
}

// ---- fallback: hwT[f][j] = sum_k h1[j][k]*w1[k][f] ----
__global__ __launch_bounds__(256) void h1w1_kernel(
        const uint16_t* __restrict__ xr,
        const float* __restrict__ h1, const void* __restrict__ w1p,
        uint16_t* __restrict__ hwT) {
    bool isbf = probe_isbf(xr);
    int t = blockIdx.x * 256 + threadIdx.x;
    int j = t >> 4;
    int f0 = (t & 15) * 8;
    float acc[8] = {0.f,0.f,0.f,0.f,0.f,0.f,0.f,0.f};
    const float* hrow = h1 + (size_t)j * FOUT;
    if (isbf) {
        const uint16_t* w1 = (const uint16_t*)w1p;
        for (int k4 = 0; k4 < FOUT; k4 += 4) {
            float4 a4 = *(const float4*)(hrow + k4);
            float av[4] = {a4.x, a4.y, a4.z, a4.w};
            #pragma unroll
            for (int i = 0; i < 4; i++) {
                u16x8 wv = *(const u16x8*)(w1 + (size_t)(k4 + i) * FOUT + f0);
                #pragma unroll
                for (int q = 0; q < 8; q++) acc[q] += av[i] * bf2f(wv[q]);
            }
        }
    } else {
        const float* w1 = (const float*)w1p;
        for (int k4 = 0; k4 < FOUT; k4 += 4) {
            float4 a4 = *(const float4*)(hrow + k4);
            float av[4] = {a4.x, a4.y, a4.z, a4.w};
            #pragma unroll
            for (int i = 0; i < 4; i++) {
                const float* wr = w1 + (size_t)(k4 + i) * FOUT + f0;
                float4 wa = *(const float4*)wr;
                float4 wb = *(const float4*)(wr + 4);
                acc[0] += av[i]*wa.x; acc[1] += av[i]*wa.y;
                acc[2] += av[i]*wa.z; acc[3] += av[i]*wa.w;
                acc[4] += av[i]*wb.x; acc[5] += av[i]*wb.y;
                acc[6] += av[i]*wb.z; acc[7] += av[i]*wb.w;
            }
        }
    }
    #pragma unroll
    for (int q = 0; q < 8; q++) hwT[(size_t)(f0 + q) * NN + j] = f2bf(acc[q]);
}

// ---- fallback: out = 0.5*(h1+h2), dtype per probe ----
__global__ __launch_bounds__(256) void final_kernel(
        const uint16_t* __restrict__ xr,
        const float* __restrict__ h1, const float* __restrict__ h2,
        void* __restrict__ outp) {
    bool isbf = probe_isbf(xr);
    int idx = (blockIdx.x * 256 + threadIdx.x) * 4;
    float4 a = *(const float4*)(h1 + idx);
    float4 b = *(const float4*)(h2 + idx);
    float4 r = make_float4(0.5f*(a.x+b.x), 0.5f*(a.y+b.y), 0.5f*(a.z+b.z), 0.5f*(a.w+b.w));
    if (isbf) {
        ushort4 ov = make_ushort4(f2bf(r.x), f2bf(r.y), f2bf(r.z), f2bf(r.w));
        *(ushort4*)((uint16_t*)outp + idx) = ov;
    } else {
        *(float4*)((float*)outp + idx) = r;
    }
}

extern "C" void kernel_launch(void* const* d_in, const int* in_sizes, int n_in,
                              void* d_out, int out_size, void* d_ws, size_t ws_size,
                              hipStream_t stream) {
    char* ws = (char*)d_ws;
    uint16_t* xw0T = (uint16_t*)(ws);
    uint16_t* hwT  = (uint16_t*)(ws + (2u << 20));
    float*    h1   = (float*)   (ws + (4u << 20));
    float*    h2   = (float*)   (ws + (8u << 20));
    uint16_t* sym  = (uint16_t*)(ws + (13u << 20));
    float*    P    = (float*)   (ws + ((size_t)144 << 20));
    const uint16_t* xr = (const uint16_t*)d_in[0];
    // P ends at 144MB + SPLITK*8192*128*4 = 160MB
    const size_t need_fast = ((size_t)144 << 20)
                           + (size_t)SPLITK * NN * FOUT * 4 + (1u << 20);
    const bool fast = ws_size >= need_fast;

    xw0_kernel<<<512, 256, 0, stream>>>(d_in[0], d_in[2], xw0T);
    if (fast) {
        sym_kernel<<<dim3(128, 65), 256, 0, stream>>>(xr, d_in[1], d_in[6], sym);
        gemm_part_kernel<<<dim3(256, SPLITK), 256, 0, stream>>>(sym, xw0T, P);
        reduce1_kernel<<<512, 256, 0, stream>>>(xr, P, d_in[3], d_in[4], h1, hwT);
        gemm_part_kernel<<<dim3(256, SPLITK), 256, 0, stream>>>(sym, hwT, P);
        reduce2_kernel<<<1024, 256, 0, stream>>>(xr, P, d_in[5], h1, d_out);
    } else {
        init_bias_kernel<<<1024, 256, 0, stream>>>(xr, d_in[3], d_in[5], h1, h2);
        gemm_otf_kernel<<<dim3(64, SPLITK), 256, 0, stream>>>(xr, d_in[1], xw0T, h1, d_in[6]);
        h1w1_kernel<<<512, 256, 0, stream>>>(xr, h1, d_in[4], hwT);
        gemm_otf_kernel<<<dim3(64, SPLITK), 256, 0, stream>>>(xr, d_in[1], hwT, h2, d_in[6]);
        final_kernel<<<1024, 256, 0, stream>>>(xr, h1, h2, d_out);
    }
}